// Round 2
// baseline (555.941 us; speedup 1.0000x reference)
//
#include <hip/hip_runtime.h>
#include <hip/hip_bf16.h>

#define NB 4
#define NH 180
#define NW 320
#define NC 64
#define NSCAN (NB*NH)                    // 720
#define NROWS (NB*NH*NW)                 // 230400
#define NELEM ((size_t)NROWS*NC)         // 14745600

using short8  = __attribute__((ext_vector_type(8))) short;
using floatx4 = __attribute__((ext_vector_type(4))) float;

__device__ __forceinline__ float bflo(unsigned int u) { return __uint_as_float(u << 16); }
__device__ __forceinline__ float bfhi(unsigned int u) { return __uint_as_float(u & 0xffff0000u); }

__device__ __forceinline__ unsigned short fbf(float f) {
    __hip_bfloat16 h = __float2bfloat16(f);
    unsigned short s; __builtin_memcpy(&s, &h, 2); return s;
}
__device__ __forceinline__ unsigned int packbf(float lo, float hi) {
    return (unsigned int)fbf(lo) | ((unsigned int)fbf(hi) << 16);
}

// 0.125 * log2(e) — folded into q_l at projection time (exactly one factor
// per score product regardless of direction), so attn uses exp2f(s) directly.
#define SCALE_LOG2E 0.18033688011112042f

// -------------------------------------------------------------------------
// Kernel 1: fused LayerNorm + 4 projections.
// p=0,1 (q_l,q_r): normal [row][c] bf16 layout.  p=0 additionally pre-scaled
// by 0.125*log2e (score scale folded in).
// p=2,3 (v_l,v_r): TRANSPOSED per-scanline layout vT[scan][c][w] (64x320).
// grid (900, 4) remapped so the q- and v-projection of the SAME x-tile run
// back-to-back on the SAME XCD (x staged once into that XCD's L2, read 2x).
// block 256.  mfma_f32_16x16x32_bf16.
// -------------------------------------------------------------------------
__global__ __launch_bounds__(256) void proj_kernel(
    const float* __restrict__ xl, const float* __restrict__ xr,
    const float* __restrict__ lsl, const float* __restrict__ lbl,
    const float* __restrict__ lsr, const float* __restrict__ lbr,
    const float* __restrict__ wql, const float* __restrict__ bql,
    const float* __restrict__ wqr, const float* __restrict__ bqr,
    const float* __restrict__ wvl, const float* __restrict__ bvl,
    const float* __restrict__ wvr, const float* __restrict__ bvr,
    __hip_bfloat16* __restrict__ ql, __hip_bfloat16* __restrict__ qr,
    __hip_bfloat16* __restrict__ vlT, __hip_bfloat16* __restrict__ vrT)
{
    // bijective XCD remap over 3600 blocks (= 8 XCDs * 450):
    // g enumerates (tile, side, kind) with kind (q vs v) fastest -> the two
    // readers of one x-tile are XCD-colocated and temporally adjacent.
    const int flat = blockIdx.x + 900 * blockIdx.y;
    const int g    = (flat & 7) * 450 + (flat >> 3);
    const int kind = g & 1;            // 0 = q-proj, 1 = v-proj
    const int pairid = g >> 1;         // 0..1799
    const int side = pairid & 1;       // 0 = left, 1 = right
    const int tile = pairid >> 1;      // 0..899
    const int p    = side + 2 * kind;  // original p semantics
    const int t    = threadIdx.x;
    const int row0 = tile * 256;

    const float* src  = (p == 0 || p == 2) ? xl : xr;
    const float* Wm   = (p == 0) ? wql : (p == 1) ? wqr : (p == 2) ? wvl : wvr;
    const float* bias = (p == 0) ? bql : (p == 1) ? bqr : (p == 2) ? bvl : bvr;
    __hip_bfloat16* dst = (p == 0) ? ql : (p == 1) ? qr : (p == 2) ? vlT : vrT;
    const bool doLN = (p < 2);
    const float* lns = (p == 0) ? lsl : lsr;
    const float* lnb = (p == 0) ? lbl : lbr;
    const float oscale = (p == 0) ? SCALE_LOG2E : 1.0f;

    __shared__ __align__(16) __hip_bfloat16 sA[256 * 72];   // 36864 B
    __shared__ __align__(16) __hip_bfloat16 sWt[64 * 72];   // 9216 B : sWt[n*72+k] = W[k][n]
    __shared__ float sLs[64], sLb[64], sBias[64];

    if (t < 64) {
        sLs[t]   = doLN ? lns[t] : 1.0f;
        sLb[t]   = doLN ? lnb[t] : 0.0f;
        sBias[t] = bias[t];
    }
    // stage W transposed (fp32 -> bf16)
    {
        const int k  = t >> 2;
        const int c0 = (t & 3) * 16;
        const float4* wrow = (const float4*)(Wm + k * NC + c0);
        float wv[16];
#pragma unroll
        for (int j = 0; j < 4; ++j) {
            float4 w4 = wrow[j];
            wv[4*j] = w4.x; wv[4*j+1] = w4.y; wv[4*j+2] = w4.z; wv[4*j+3] = w4.w;
        }
#pragma unroll
        for (int j = 0; j < 16; ++j)
            sWt[(c0 + j) * 72 + k] = __float2bfloat16(wv[j]);
    }
    __syncthreads();

    // Phase 1: thread t owns row (row0 + t): fp32 load, (LN), bf16 pack into sA
    {
        const float4* x4 = (const float4*)(src + (size_t)(row0 + t) * NC);
        float f[64];
#pragma unroll
        for (int j = 0; j < 16; ++j) {
            float4 v = x4[j];
            f[4*j] = v.x; f[4*j+1] = v.y; f[4*j+2] = v.z; f[4*j+3] = v.w;
        }
        if (doLN) {
            float s = 0.f, s2 = 0.f;
#pragma unroll
            for (int c = 0; c < 64; ++c) { s += f[c]; s2 = fmaf(f[c], f[c], s2); }
            const float mu   = s * (1.0f / 64.0f);
            const float var  = s2 * (1.0f / 64.0f) - mu * mu;
            const float rstd = rsqrtf(var + 1e-6f);
#pragma unroll
            for (int c = 0; c < 64; ++c) f[c] = (f[c] - mu) * rstd * sLs[c] + sLb[c];
        }
        unsigned int* arow = (unsigned int*)&sA[t * 72];
#pragma unroll
        for (int j = 0; j < 32; ++j) arow[j] = packbf(f[2*j], f[2*j+1]);
    }
    __syncthreads();

    // Phase 2: MFMA.
    const int lane = t & 63;
    const int wv_  = t >> 6;
    const int quad = lane >> 4;
    const int mn   = lane & 15;

    short8 bfr[4][2];
#pragma unroll
    for (int nt = 0; nt < 4; ++nt)
#pragma unroll
        for (int ks = 0; ks < 2; ++ks)
            bfr[nt][ks] = *(const short8*)&sWt[(nt * 16 + mn) * 72 + ks * 32 + quad * 8];

#pragma unroll
    for (int mt = 0; mt < 4; ++mt) {
        const int rl = wv_ * 64 + mt * 16 + mn;
        short8 a0 = *(const short8*)&sA[rl * 72 +      quad * 8];
        short8 a1 = *(const short8*)&sA[rl * 72 + 32 + quad * 8];
#pragma unroll
        for (int nt = 0; nt < 4; ++nt) {
            floatx4 c = {0.f, 0.f, 0.f, 0.f};
            c = __builtin_amdgcn_mfma_f32_16x16x32_bf16(a0, bfr[nt][0], c, 0, 0, 0);
            c = __builtin_amdgcn_mfma_f32_16x16x32_bf16(a1, bfr[nt][1], c, 0, 0, 0);
            const int col = nt * 16 + mn;
            const float bb = sBias[col];
            if (p < 2) {
#pragma unroll
                for (int i = 0; i < 4; ++i) {
                    const int rowl = wv_ * 64 + mt * 16 + quad * 4 + i;
                    dst[(size_t)(row0 + rowl) * NC + col] =
                        __float2bfloat16((c[i] + bb) * oscale);
                }
            } else {
#pragma unroll
                for (int i = 0; i < 4; ++i) {
                    const unsigned grow = (unsigned)(row0 + wv_ * 64 + mt * 16 + quad * 4 + i);
                    const unsigned sc   = grow / 320u;
                    const unsigned wr   = grow - sc * 320u;
                    dst[(size_t)sc * (NC * NW) + (unsigned)col * NW + wr] =
                        __float2bfloat16(c[i] + bb);
                }
            }
        }
    }
}

// -------------------------------------------------------------------------
// Kernel 2: MFMA bidirectional scanline attention, BARRIER-FREE.
// K/VT fragments load straight from global (XCD-local L2 resident — round-1
// counters: FETCH dropped 374->118 MB with the swizzle, so staging them
// through LDS was pure overhead, cf. learn_hip m169).  All remaining LDS
// (P slab, O redistribution, 1/rs) is per-wave -> zero __syncthreads.
// grid (5, 720, 2) remapped bijectively across 8 XCDs.  block 256 (4 waves
// share L1 for the K/VT fragments).
// dir 0: Q=q_l, K=q_r, V=v_r (row softmax)  -> out0 = x_l + beta * O/rs
// dir 1: Q=q_r, K=q_l, V=v_l (col softmax)  -> out1 = x_r + gamma * O/rs
// -------------------------------------------------------------------------
__global__ __launch_bounds__(256, 5) void attn_kernel(
    const __hip_bfloat16* __restrict__ ql, const __hip_bfloat16* __restrict__ qr,
    const __hip_bfloat16* __restrict__ vlT, const __hip_bfloat16* __restrict__ vrT,
    const float* __restrict__ xl, const float* __restrict__ xr,
    const float* __restrict__ beta, const float* __restrict__ gamma,
    float* __restrict__ out)
{
    // bijective XCD-aware remap: 7200 blocks = 8 XCDs * 900.
    const int flat = blockIdx.x + 5 * (blockIdx.y + 720 * blockIdx.z);
    const int g    = (flat & 7) * 900 + (flat >> 3);
    const int mt   = g % 5;            // 0..4
    const int s2   = g / 5;            // 0..1439
    const int p    = s2 & 1;           // 0..1
    const int scan = s2 >> 1;          // 0..719

    const int t    = threadIdx.x;
    const int lane = t & 63;
    const int w    = t >> 6;
    const int quad = lane >> 4;
    const int mn   = lane & 15;
    const int m0   = mt * 64;

    const __hip_bfloat16* Q  = (p ? qr  : ql ) + (size_t)scan * (NW * NC);
    const __hip_bfloat16* K  = (p ? ql  : qr ) + (size_t)scan * (NW * NC);
    const __hip_bfloat16* VT = (p ? vlT : vrT) + (size_t)scan * (NC * NW);
    const float* xS = p ? xr : xl;
    const float* gv = p ? gamma : beta;

    // Per-wave LDS slab, union of:
    //   P : 16 rows x 72 bf16 = 2304 B   (QK^T->exp tile, wave-local)
    //   O : 16 rows x 68 f32  = 4352 B   (epilogue redistribution, wave-local)
    // stride 4608 B.  All accesses wave-local -> no barriers anywhere.
    __shared__ __align__(16) char sW[4 * 4608];              // 18432 B
    __shared__ float sRS[64];
    __hip_bfloat16* sP  = (__hip_bfloat16*)(sW + w * 4608);
    float*          sOw = (float*)(sW + w * 4608);

    // Q B-frags straight from global: wave w owns Q rows m0+w*16 .. +15.
    const __hip_bfloat16* qrow = Q + (size_t)(m0 + w * 16 + mn) * NC;
    const short8 qa0 = *(const short8*)(qrow + quad * 8);
    const short8 qa1 = *(const short8*)(qrow + 32 + quad * 8);

    floatx4 acc[4];
#pragma unroll
    for (int nt = 0; nt < 4; ++nt) acc[nt] = (floatx4){0.f, 0.f, 0.f, 0.f};
    float rs = 0.f;

    for (int rb = 0; rb < NW; rb += 64) {
        __builtin_amdgcn_s_setprio(1);
        // swapped QK^T: S^T = K_tile * Q^T.  K A-frags direct from global/L2.
        // Lane (quad,mn) holds P[m = w*16+mn][r = rt*16 + quad*4 + i] ->
        // f32 row-sum in-register, pack pairs, b64 store to wave-local slab.
#pragma unroll
        for (int rt = 0; rt < 4; ++rt) {
            const __hip_bfloat16* kr = K + (size_t)(rb + rt * 16 + mn) * NC + quad * 8;
            const short8 ka0 = *(const short8*)kr;
            const short8 ka1 = *(const short8*)(kr + 32);
            floatx4 s = {0.f, 0.f, 0.f, 0.f};
            s = __builtin_amdgcn_mfma_f32_16x16x32_bf16(ka0, qa0, s, 0, 0, 0);
            s = __builtin_amdgcn_mfma_f32_16x16x32_bf16(ka1, qa1, s, 0, 0, 0);
            const float e0 = exp2f(s[0]), e1 = exp2f(s[1]);
            const float e2 = exp2f(s[2]), e3 = exp2f(s[3]);
            rs += (e0 + e1) + (e2 + e3);
            uint2 pk; pk.x = packbf(e0, e1); pk.y = packbf(e2, e3);
            *(uint2*)&sP[mn * 72 + rt * 16 + quad * 4] = pk;
        }

        // PV (contract r): A = P rows (m=mn) from wave-local slab,
        // B = VT rows (c = nt*16+mn) direct from global/L2.
#pragma unroll
        for (int ks = 0; ks < 2; ++ks) {
            const short8 pa = *(const short8*)&sP[mn * 72 + ks * 32 + quad * 8];
#pragma unroll
            for (int nt = 0; nt < 4; ++nt) {
                const __hip_bfloat16* vr =
                    VT + (size_t)(nt * 16 + mn) * NW + rb + ks * 32 + quad * 8;
                const short8 vb = *(const short8*)vr;
                acc[nt] = __builtin_amdgcn_mfma_f32_16x16x32_bf16(pa, vb, acc[nt], 0, 0, 0);
            }
        }
        __builtin_amdgcn_s_setprio(0);
    }

    // finish row sums: quads hold disjoint r-subsets of row (w*16+mn)
    rs += __shfl_xor(rs, 16);
    rs += __shfl_xor(rs, 32);

    if (lane < 16) sRS[w * 16 + lane] = 1.0f / rs;   // lane<16 => mn==lane

    // O redistribution into the wave's own slab (overlays dead P region;
    // WAR on same-wave LDS is ordered by lgkmcnt — no barrier needed).
#pragma unroll
    for (int nt = 0; nt < 4; ++nt)
#pragma unroll
        for (int i = 0; i < 4; ++i)
            sOw[(quad * 4 + i) * 68 + nt * 16 + mn] = acc[nt][i];

    // epilogue: thread t handles row m = t>>2 — provably in its OWN wave
    // (m>>4 == t>>6), so no cross-wave LDS dependency.
    {
        const int m = t >> 2, c0 = (t & 3) * 16;
        const float inv = sRS[m];
        const int grow = scan * NW + m0 + m;
        const float4* xg = (const float4*)(xS + (size_t)grow * NC + c0);
        const float4* gg = (const float4*)(gv + c0);
        const float4* so = (const float4*)((const float*)(sW + (m >> 4) * 4608)
                                           + (m & 15) * 68 + c0);
        float4* og = (float4*)(out + (p ? NELEM : (size_t)0) + (size_t)grow * NC + c0);
#pragma unroll
        for (int j = 0; j < 4; ++j) {
            float4 xv = xg[j];
            float4 gvv = gg[j];
            float4 ov = so[j];
            float4 o;
            o.x = xv.x + ov.x * inv * gvv.x;
            o.y = xv.y + ov.y * inv * gvv.y;
            o.z = xv.z + ov.z * inv * gvv.z;
            o.w = xv.w + ov.w * inv * gvv.w;
            og[j] = o;
        }
    }
}

extern "C" void kernel_launch(void* const* d_in, const int* in_sizes, int n_in,
                              void* d_out, int out_size, void* d_ws, size_t ws_size,
                              hipStream_t stream)
{
    const float* xl  = (const float*)d_in[0];
    const float* xr  = (const float*)d_in[1];
    const float* lsl = (const float*)d_in[2];
    const float* lbl = (const float*)d_in[3];
    const float* lsr = (const float*)d_in[4];
    const float* lbr = (const float*)d_in[5];
    const float* wql = (const float*)d_in[6];
    const float* bql = (const float*)d_in[7];
    const float* wqr = (const float*)d_in[8];
    const float* bqr = (const float*)d_in[9];
    const float* wvl = (const float*)d_in[10];
    const float* bvl = (const float*)d_in[11];
    const float* wvr = (const float*)d_in[12];
    const float* bvr = (const float*)d_in[13];
    const float* beta  = (const float*)d_in[14];
    const float* gamma = (const float*)d_in[15];

    __hip_bfloat16* ws   = (__hip_bfloat16*)d_ws;
    __hip_bfloat16* ql_  = ws;
    __hip_bfloat16* qr_  = ws + NELEM;
    __hip_bfloat16* vlT_ = ws + 2 * NELEM;
    __hip_bfloat16* vrT_ = ws + 3 * NELEM;

    proj_kernel<<<dim3(900, 4, 1), 256, 0, stream>>>(
        xl, xr, lsl, lbl, lsr, lbr, wql, bql, wqr, bqr, wvl, bvl, wvr, bvr,
        ql_, qr_, vlT_, vrT_);

    attn_kernel<<<dim3(5, NSCAN, 2), 256, 0, stream>>>(
        ql_, qr_, vlT_, vrT_, xl, xr, beta, gamma, (float*)d_out);
}

// Round 3
// 363.963 us; speedup vs baseline: 1.5275x; 1.5275x over previous
//
#include <hip/hip_runtime.h>
#include <hip/hip_bf16.h>

#define NB 4
#define NH 180
#define NW 320
#define NC 64
#define NSCAN (NB*NH)                    // 720
#define NROWS (NB*NH*NW)                 // 230400
#define NELEM ((size_t)NROWS*NC)         // 14745600

using short8  = __attribute__((ext_vector_type(8))) short;
using floatx4 = __attribute__((ext_vector_type(4))) float;
using uint2v  = __attribute__((ext_vector_type(2))) unsigned int;

__device__ __forceinline__ unsigned short fbf(float f) {
    __hip_bfloat16 h = __float2bfloat16(f);
    unsigned short s; __builtin_memcpy(&s, &h, 2); return s;
}
__device__ __forceinline__ unsigned int packbf(float lo, float hi) {
    return (unsigned int)fbf(lo) | ((unsigned int)fbf(hi) << 16);
}

// Two-register lane-row swaps (gfx950 permlane*_swap; shfl fallback).
// SWAP32: a' = [a.r0, a.r1, b.r0, b.r1], b' = [a.r2, a.r3, b.r2, b.r3]
// SWAP16: a' = [a.r0, b.r0, a.r2, b.r2], b' = [a.r1, b.r1, a.r3, b.r3]
// (rows = 16-lane groups)
__device__ __forceinline__ void swap32(unsigned& a, unsigned& b, int lane) {
#if __has_builtin(__builtin_amdgcn_permlane32_swap)
    uint2v r = __builtin_amdgcn_permlane32_swap(a, b, false, false);
    a = r.x; b = r.y;
#else
    unsigned as = __shfl_xor(a, 32), bs = __shfl_xor(b, 32);
    unsigned na = (lane < 32) ? a : bs;
    unsigned nb = (lane < 32) ? as : b;
    a = na; b = nb;
#endif
}
__device__ __forceinline__ void swap16(unsigned& a, unsigned& b, int lane) {
#if __has_builtin(__builtin_amdgcn_permlane16_swap)
    uint2v r = __builtin_amdgcn_permlane16_swap(a, b, false, false);
    a = r.x; b = r.y;
#else
    unsigned as = __shfl_xor(a, 16), bs = __shfl_xor(b, 16);
    unsigned na = (lane & 16) ? bs : a;
    unsigned nb = (lane & 16) ? b : as;
    a = na; b = nb;
#endif
}

// 0.125 * log2(e) — folded into q_l at projection time (exactly one factor
// per score product regardless of direction), so attn uses exp2f(s) directly.
#define SCALE_LOG2E 0.18033688011112042f

// -------------------------------------------------------------------------
// Kernel 1: fused LayerNorm + 4 projections.
// p=0,1 (q_l,q_r): normal [row][c] bf16 layout.  p=0 additionally pre-scaled
// by 0.125*log2e (score scale folded in).
// p=2,3 (v_l,v_r): TRANSPOSED per-scanline layout vT[scan][c][w] (64x320).
// grid (900, 4) remapped so the q- and v-projection of the SAME x-tile run
// back-to-back on the SAME XCD (x staged once into that XCD's L2, read 2x).
// block 256.  mfma_f32_16x16x32_bf16.
// -------------------------------------------------------------------------
__global__ __launch_bounds__(256) void proj_kernel(
    const float* __restrict__ xl, const float* __restrict__ xr,
    const float* __restrict__ lsl, const float* __restrict__ lbl,
    const float* __restrict__ lsr, const float* __restrict__ lbr,
    const float* __restrict__ wql, const float* __restrict__ bql,
    const float* __restrict__ wqr, const float* __restrict__ bqr,
    const float* __restrict__ wvl, const float* __restrict__ bvl,
    const float* __restrict__ wvr, const float* __restrict__ bvr,
    __hip_bfloat16* __restrict__ ql, __hip_bfloat16* __restrict__ qr,
    __hip_bfloat16* __restrict__ vlT, __hip_bfloat16* __restrict__ vrT)
{
    const int flat = blockIdx.x + 900 * blockIdx.y;
    const int g    = (flat & 7) * 450 + (flat >> 3);
    const int kind = g & 1;            // 0 = q-proj, 1 = v-proj
    const int pairid = g >> 1;         // 0..1799
    const int side = pairid & 1;       // 0 = left, 1 = right
    const int tile = pairid >> 1;      // 0..899
    const int p    = side + 2 * kind;  // original p semantics
    const int t    = threadIdx.x;
    const int row0 = tile * 256;

    const float* src  = (p == 0 || p == 2) ? xl : xr;
    const float* Wm   = (p == 0) ? wql : (p == 1) ? wqr : (p == 2) ? wvl : wvr;
    const float* bias = (p == 0) ? bql : (p == 1) ? bqr : (p == 2) ? bvl : bvr;
    __hip_bfloat16* dst = (p == 0) ? ql : (p == 1) ? qr : (p == 2) ? vlT : vrT;
    const bool doLN = (p < 2);
    const float* lns = (p == 0) ? lsl : lsr;
    const float* lnb = (p == 0) ? lbl : lbr;
    const float oscale = (p == 0) ? SCALE_LOG2E : 1.0f;

    __shared__ __align__(16) __hip_bfloat16 sA[256 * 72];   // 36864 B
    __shared__ __align__(16) __hip_bfloat16 sWt[64 * 72];   // 9216 B : sWt[n*72+k] = W[k][n]
    __shared__ float sLs[64], sLb[64], sBias[64];

    if (t < 64) {
        sLs[t]   = doLN ? lns[t] : 1.0f;
        sLb[t]   = doLN ? lnb[t] : 0.0f;
        sBias[t] = bias[t];
    }
    // stage W transposed (fp32 -> bf16)
    {
        const int k  = t >> 2;
        const int c0 = (t & 3) * 16;
        const float4* wrow = (const float4*)(Wm + k * NC + c0);
        float wv[16];
#pragma unroll
        for (int j = 0; j < 4; ++j) {
            float4 w4 = wrow[j];
            wv[4*j] = w4.x; wv[4*j+1] = w4.y; wv[4*j+2] = w4.z; wv[4*j+3] = w4.w;
        }
#pragma unroll
        for (int j = 0; j < 16; ++j)
            sWt[(c0 + j) * 72 + k] = __float2bfloat16(wv[j]);
    }
    __syncthreads();

    // Phase 1: thread t owns row (row0 + t): fp32 load, (LN), bf16 pack into sA
    {
        const float4* x4 = (const float4*)(src + (size_t)(row0 + t) * NC);
        float f[64];
#pragma unroll
        for (int j = 0; j < 16; ++j) {
            float4 v = x4[j];
            f[4*j] = v.x; f[4*j+1] = v.y; f[4*j+2] = v.z; f[4*j+3] = v.w;
        }
        if (doLN) {
            float s = 0.f, s2 = 0.f;
#pragma unroll
            for (int c = 0; c < 64; ++c) { s += f[c]; s2 = fmaf(f[c], f[c], s2); }
            const float mu   = s * (1.0f / 64.0f);
            const float var  = s2 * (1.0f / 64.0f) - mu * mu;
            const float rstd = rsqrtf(var + 1e-6f);
#pragma unroll
            for (int c = 0; c < 64; ++c) f[c] = (f[c] - mu) * rstd * sLs[c] + sLb[c];
        }
        unsigned int* arow = (unsigned int*)&sA[t * 72];
#pragma unroll
        for (int j = 0; j < 32; ++j) arow[j] = packbf(f[2*j], f[2*j+1]);
    }
    __syncthreads();

    // Phase 2: MFMA.
    const int lane = t & 63;
    const int wv_  = t >> 6;
    const int quad = lane >> 4;
    const int mn   = lane & 15;

    short8 bfr[4][2];
#pragma unroll
    for (int nt = 0; nt < 4; ++nt)
#pragma unroll
        for (int ks = 0; ks < 2; ++ks)
            bfr[nt][ks] = *(const short8*)&sWt[(nt * 16 + mn) * 72 + ks * 32 + quad * 8];

#pragma unroll
    for (int mt = 0; mt < 4; ++mt) {
        const int rl = wv_ * 64 + mt * 16 + mn;
        short8 a0 = *(const short8*)&sA[rl * 72 +      quad * 8];
        short8 a1 = *(const short8*)&sA[rl * 72 + 32 + quad * 8];
#pragma unroll
        for (int nt = 0; nt < 4; ++nt) {
            floatx4 c = {0.f, 0.f, 0.f, 0.f};
            c = __builtin_amdgcn_mfma_f32_16x16x32_bf16(a0, bfr[nt][0], c, 0, 0, 0);
            c = __builtin_amdgcn_mfma_f32_16x16x32_bf16(a1, bfr[nt][1], c, 0, 0, 0);
            const int col = nt * 16 + mn;
            const float bb = sBias[col];
            if (p < 2) {
#pragma unroll
                for (int i = 0; i < 4; ++i) {
                    const int rowl = wv_ * 64 + mt * 16 + quad * 4 + i;
                    dst[(size_t)(row0 + rowl) * NC + col] =
                        __float2bfloat16((c[i] + bb) * oscale);
                }
            } else {
#pragma unroll
                for (int i = 0; i < 4; ++i) {
                    const unsigned grow = (unsigned)(row0 + wv_ * 64 + mt * 16 + quad * 4 + i);
                    const unsigned sc   = grow / 320u;
                    const unsigned wr   = grow - sc * 320u;
                    dst[(size_t)sc * (NC * NW) + (unsigned)col * NW + wr] =
                        __float2bfloat16(c[i] + bb);
                }
            }
        }
    }
}

// -------------------------------------------------------------------------
// Kernel 2: MFMA bidirectional scanline attention (no-max flash: logits
// bounded, plain sum-of-exp).  Round-1 staged structure (LDS staging with
// register prefetch — proven) with the P-tile LDS round-trip replaced by
// in-register permlane redistribution, and Q loaded direct from global.
// grid (5, 720, 2) remapped bijectively across 8 XCDs.  block 256.
// dir 0: Q=q_l, K=q_r, V=v_r (row softmax)  -> out0 = x_l + beta * O/rs
// dir 1: Q=q_r, K=q_l, V=v_l (col softmax)  -> out1 = x_r + gamma * O/rs
//
// P redistribution math: after swapped QK^T, lane (quad,mn) of wave w holds
// P[m=w*16+mn][r = rt*16+quad*4+{0..3}] packed as words W[rt][s]
// (word g = rt*8+quad*2+s, g = r/2).  PV A-frag word j at lane(quad,mn) is
// g = ks*16+quad*4+j, owned by row (g%8)>>1, slot W[2ks+(g>>3 - 2ks)][g&1].
// For each (ks,s): SWAP32(W[2ks][s], W[2ks+1][s]) then SWAP16 yields BOTH
// fragment words j=s (first output) and j=s+2 (second output).  8 swap
// instructions replace 4 ds_write_b64 + 2 ds_read_b128 + lgkm round-trip.
// -------------------------------------------------------------------------
__global__ __launch_bounds__(256, 6) void attn_kernel(
    const __hip_bfloat16* __restrict__ ql, const __hip_bfloat16* __restrict__ qr,
    const __hip_bfloat16* __restrict__ vlT, const __hip_bfloat16* __restrict__ vrT,
    const float* __restrict__ xl, const float* __restrict__ xr,
    const float* __restrict__ beta, const float* __restrict__ gamma,
    float* __restrict__ out)
{
    // bijective XCD-aware remap: 7200 blocks = 8 XCDs * 900.
    const int flat = blockIdx.x + 5 * (blockIdx.y + 720 * blockIdx.z);
    const int g    = (flat & 7) * 900 + (flat >> 3);
    const int mt   = g % 5;            // 0..4
    const int s2   = g / 5;            // 0..1439
    const int p    = s2 & 1;           // 0..1
    const int scan = s2 >> 1;          // 0..719

    const int t    = threadIdx.x;
    const int lane = t & 63;
    const int w    = t >> 6;
    const int quad = lane >> 4;
    const int mn   = lane & 15;
    const int m0   = mt * 64;

    const __hip_bfloat16* Q  = (p ? qr  : ql ) + (size_t)scan * (NW * NC);
    const __hip_bfloat16* K  = (p ? ql  : qr ) + (size_t)scan * (NW * NC);
    const __hip_bfloat16* VT = (p ? vlT : vrT) + (size_t)scan * (NC * NW);
    const float* xS = p ? xr : xl;
    const float* gv = p ? gamma : beta;

    __shared__ __align__(16) char sU[18432];                // sK+sVt  OR  sO
    __shared__ float sRS[64];
    __hip_bfloat16* sK  = (__hip_bfloat16*)sU;              // 64*72 bf16
    __hip_bfloat16* sVt = (__hip_bfloat16*)(sU + 9216);     // 64*72 bf16
    float* sO = (float*)sU;                                  // 64*68 fp32 (17408 B)

    const int sr  = t >> 2;            // staging row 0..63
    const int sc0 = (t & 3) * 16;      // staging col offset (elements)

    // prefetch chunk 0 (K rows 0..63, VT cols 0..63) into registers
    uint4 rk0, rk1, rv0, rv1;
    {
        const uint4* gk = (const uint4*)(K + (size_t)sr * NC + sc0);
        rk0 = gk[0]; rk1 = gk[1];
        const uint4* gt = (const uint4*)(VT + (size_t)sr * NW + sc0);
        rv0 = gt[0]; rv1 = gt[1];
    }

    // Q B-frags direct from global (L2-resident, one-time):
    // wave w owns Q rows m0+w*16 .. +15.
    const __hip_bfloat16* qrow = Q + (size_t)(m0 + w * 16 + mn) * NC;
    const short8 qa0 = *(const short8*)(qrow + quad * 8);
    const short8 qa1 = *(const short8*)(qrow + 32 + quad * 8);

    floatx4 acc[4];
#pragma unroll
    for (int nt = 0; nt < 4; ++nt) acc[nt] = (floatx4){0.f, 0.f, 0.f, 0.f};
    float rs = 0.f;

    for (int rb = 0; rb < NW; rb += 64) {
        __syncthreads();   // prior chunk's sK/sVt reads done
        {
            uint4* dk = (uint4*)&sK [sr * 72 + sc0]; dk[0] = rk0; dk[1] = rk1;
            uint4* dv = (uint4*)&sVt[sr * 72 + sc0]; dv[0] = rv0; dv[1] = rv1;
        }
        __syncthreads();   // sK/sVt ready

        // issue next chunk's global loads now; they complete under the compute
        if (rb + 64 < NW) {
            const uint4* gk = (const uint4*)(K + (size_t)(rb + 64 + sr) * NC + sc0);
            rk0 = gk[0]; rk1 = gk[1];
            const uint4* gt = (const uint4*)(VT + (size_t)sr * NW + (rb + 64) + sc0);
            rv0 = gt[0]; rv1 = gt[1];
        }

        __builtin_amdgcn_s_setprio(1);
        // swapped QK^T: S^T = K_tile * Q^T.  Lane (quad,mn) holds
        // P[m = w*16+mn][r = rt*16 + quad*4 + i]; f32 row-sum in-register,
        // pack pairs into W[rt][s] words — NO LDS for P.
        unsigned w0[4], w1[4];
#pragma unroll
        for (int rt = 0; rt < 4; ++rt) {
            short8 ka0 = *(const short8*)&sK[(rt * 16 + mn) * 72 +      quad * 8];
            short8 ka1 = *(const short8*)&sK[(rt * 16 + mn) * 72 + 32 + quad * 8];
            floatx4 s = {0.f, 0.f, 0.f, 0.f};
            s = __builtin_amdgcn_mfma_f32_16x16x32_bf16(ka0, qa0, s, 0, 0, 0);
            s = __builtin_amdgcn_mfma_f32_16x16x32_bf16(ka1, qa1, s, 0, 0, 0);
            const float e0 = exp2f(s[0]), e1 = exp2f(s[1]);
            const float e2 = exp2f(s[2]), e3 = exp2f(s[3]);
            rs += (e0 + e1) + (e2 + e3);
            w0[rt] = packbf(e0, e1);
            w1[rt] = packbf(e2, e3);
        }

        // PV (contract r): A-frag assembled in-register from W via swaps,
        // B = Vt rows from LDS.
#pragma unroll
        for (int ks = 0; ks < 2; ++ks) {
            unsigned a0 = w0[2 * ks], b0 = w0[2 * ks + 1];
            swap32(a0, b0, lane); swap16(a0, b0, lane);   // a0=O[0], b0=O[2]
            unsigned a1 = w1[2 * ks], b1 = w1[2 * ks + 1];
            swap32(a1, b1, lane); swap16(a1, b1, lane);   // a1=O[1], b1=O[3]
            uint4 pu; pu.x = a0; pu.y = a1; pu.z = b0; pu.w = b1;
            short8 pa; __builtin_memcpy(&pa, &pu, 16);
#pragma unroll
            for (int nt = 0; nt < 4; ++nt) {
                short8 vb = *(const short8*)&sVt[(nt * 16 + mn) * 72 + ks * 32 + quad * 8];
                acc[nt] = __builtin_amdgcn_mfma_f32_16x16x32_bf16(pa, vb, acc[nt], 0, 0, 0);
            }
        }
        __builtin_amdgcn_s_setprio(0);
    }

    // finish row sums: quads hold disjoint r-subsets of row (w*16+mn)
    rs += __shfl_xor(rs, 16);
    rs += __shfl_xor(rs, 32);

    __syncthreads();   // all PV reads of sVt done -> sU reusable as sO

    if (lane < 16) sRS[w * 16 + lane] = 1.0f / rs;   // lane<16 => mn==lane
#pragma unroll
    for (int nt = 0; nt < 4; ++nt)
#pragma unroll
        for (int i = 0; i < 4; ++i)
            sO[(w * 16 + quad * 4 + i) * 68 + nt * 16 + mn] = acc[nt][i];

    // epilogue: thread t handles row m = t>>2 — same wave (m>>4 == t>>6),
    // so same-wave LDS ordering suffices (no barrier).
    {
        const int m = t >> 2, c0 = (t & 3) * 16;
        const float inv = sRS[m];
        const int grow = scan * NW + m0 + m;
        const float4* xg = (const float4*)(xS + (size_t)grow * NC + c0);
        const float4* gg = (const float4*)(gv + c0);
        const float4* so = (const float4*)&sO[m * 68 + c0];
        float4* og = (float4*)(out + (p ? NELEM : (size_t)0) + (size_t)grow * NC + c0);
#pragma unroll
        for (int j = 0; j < 4; ++j) {
            float4 xv = xg[j];
            float4 gvv = gg[j];
            float4 ov = so[j];
            float4 o;
            o.x = xv.x + ov.x * inv * gvv.x;
            o.y = xv.y + ov.y * inv * gvv.y;
            o.z = xv.z + ov.z * inv * gvv.z;
            o.w = xv.w + ov.w * inv * gvv.w;
            og[j] = o;
        }
    }
}

extern "C" void kernel_launch(void* const* d_in, const int* in_sizes, int n_in,
                              void* d_out, int out_size, void* d_ws, size_t ws_size,
                              hipStream_t stream)
{
    const float* xl  = (const float*)d_in[0];
    const float* xr  = (const float*)d_in[1];
    const float* lsl = (const float*)d_in[2];
    const float* lbl = (const float*)d_in[3];
    const float* lsr = (const float*)d_in[4];
    const float* lbr = (const float*)d_in[5];
    const float* wql = (const float*)d_in[6];
    const float* bql = (const float*)d_in[7];
    const float* wqr = (const float*)d_in[8];
    const float* bqr = (const float*)d_in[9];
    const float* wvl = (const float*)d_in[10];
    const float* bvl = (const float*)d_in[11];
    const float* wvr = (const float*)d_in[12];
    const float* bvr = (const float*)d_in[13];
    const float* beta  = (const float*)d_in[14];
    const float* gamma = (const float*)d_in[15];

    __hip_bfloat16* ws   = (__hip_bfloat16*)d_ws;
    __hip_bfloat16* ql_  = ws;
    __hip_bfloat16* qr_  = ws + NELEM;
    __hip_bfloat16* vlT_ = ws + 2 * NELEM;
    __hip_bfloat16* vrT_ = ws + 3 * NELEM;

    proj_kernel<<<dim3(900, 4, 1), 256, 0, stream>>>(
        xl, xr, lsl, lbl, lsr, lbr, wql, bql, wqr, bqr, wvl, bvl, wvr, bvr,
        ql_, qr_, vlT_, vrT_);

    attn_kernel<<<dim3(5, NSCAN, 2), 256, 0, stream>>>(
        ql_, qr_, vlT_, vrT_, xl, xr, beta, gamma, (float*)d_out);
}